// Round 12
// baseline (211.465 us; speedup 1.0000x reference)
//
#include <hip/hip_runtime.h>
#include <hip/hip_bf16.h>

// Problem constants (B=8192, D=512 from reference setup_inputs)
#define BN_ 8192
#define DK_ 512
#define TEMP_INV 14.2857142857142857f   // 1/0.07
#define LOG2E_ 1.44269504088896f
#define MAXOFF 15.0f                    // fixed lse offset; |sim| < 14.29 (unit vectors)

typedef __bf16 bf16x8 __attribute__((ext_vector_type(8)));
typedef float f32x4 __attribute__((ext_vector_type(4)));

__device__ inline unsigned short f2bf(float f) {
    unsigned u = __float_as_uint(f);
    return (unsigned short)((u + 0x7FFFu + ((u >> 16) & 1u)) >> 16);
}

// ---------------- Kernel 1: L2-normalize rows, write bf16 ----------------
__global__ __launch_bounds__(256) void norm_kernel(const float* __restrict__ emb,
                                                   unsigned short* __restrict__ ebf) {
    const int row  = blockIdx.x * 4 + (threadIdx.x >> 6);
    const int lane = threadIdx.x & 63;
    const float4* src = reinterpret_cast<const float4*>(emb + (size_t)row * DK_);
    float4 v0 = src[lane];
    float4 v1 = src[lane + 64];
    float ss = v0.x*v0.x + v0.y*v0.y + v0.z*v0.z + v0.w*v0.w
             + v1.x*v1.x + v1.y*v1.y + v1.z*v1.z + v1.w*v1.w;
#pragma unroll
    for (int off = 1; off < 64; off <<= 1) ss += __shfl_xor(ss, off, 64);
    const float scale = 1.0f / fmaxf(sqrtf(ss), 1e-12f);
    uint2 o0, o1;
    o0.x = (unsigned)f2bf(v0.x * scale) | ((unsigned)f2bf(v0.y * scale) << 16);
    o0.y = (unsigned)f2bf(v0.z * scale) | ((unsigned)f2bf(v0.w * scale) << 16);
    o1.x = (unsigned)f2bf(v1.x * scale) | ((unsigned)f2bf(v1.y * scale) << 16);
    o1.y = (unsigned)f2bf(v1.z * scale) | ((unsigned)f2bf(v1.w * scale) << 16);
    uint2* dst = reinterpret_cast<uint2*>(ebf + (size_t)row * DK_);
    dst[lane]      = o0;
    dst[lane + 64] = o1;
}

// ---------------- Kernel 2: triangular (cb >= rb) on the r11 base ----------------
// r11 machinery kept verbatim: single-buffer LDS (4 blocks/CU), T2 both-sides XOR
// swizzle (conflict-free ds_read_b128), counted-vmcnt mask register pipeline, raw
// s_barrier pair per kt.  New: only 2080 tiles; off-diag tiles also credit cb-rows
// via symmetry (col-side epilogue, r8-verified); BOTH mask orientations pipelined
// (4 int4 in flight -> vmcnt(4)).  Queue at the wait (kt<7):
//   [m(kt)4 | STAGE(kt)8 | m(kt+1)4] -> vmcnt(4) completes m(kt)+stage(kt).
// SWAPPED mfma operands (verified r5/r6): a = acc[fm][fn][rg] is sim(i,j) with
//   i = rb*128 + wr*64 + fm*16 + (lane&15)
//   j = cb*128 + wc*64 + fn*16 + (lane>>4)*4 + rg
__global__ __launch_bounds__(256, 4) void infonce_main(
    const unsigned short* __restrict__ ebf,
    const int* __restrict__ mask,
    float* __restrict__ se, float* __restrict__ ps, float* __restrict__ ct) {

    __shared__ unsigned short As[128 * 64];       // 16KB
    __shared__ unsigned short Bs[128 * 64];       // 16KB
    __shared__ unsigned char  pmB [128 * 16];     // 2KB bits mask[rb-rows][cb-cols]
    __shared__ unsigned char  pmBT[128 * 16];     // 2KB bits mask[cb-rows][rb-cols]
    __shared__ float redR[2][128];                // rb-row partials {lse, pos}
    __shared__ float redC[2][128];                // cb-row partials {lse, pos}

    const int t    = threadIdx.x;
    const int lane = t & 63;
    const int wid  = t >> 6;
    const int wr   = wid >> 1;
    const int wc   = wid & 1;

    // triangular decode (verified r4/r7/r8): base(r) = 64r - r(r-1)/2
    const int bid = blockIdx.x;
    int rb = (int)((129.0f - sqrtf(16641.0f - 8.0f * (float)bid)) * 0.5f);
    while (64 * (rb + 1) - ((rb + 1) * rb) / 2 <= bid) ++rb;
    while (64 * rb - (rb * (rb - 1)) / 2 > bid) --rb;
    const int cb = rb + (bid - (64 * rb - (rb * (rb - 1)) / 2));
    const bool offd = (rb != cb);
    const bool db   = !offd;

    if (t < 128) { redR[0][t] = 0.f; redR[1][t] = 0.f; redC[0][t] = 0.f; redC[1][t] = 0.f; }

    f32x4 acc[4][4] = {};

    // ebf staging: thread t -> row t/8; global source chunk PRE-SWIZZLED (r11):
    // linear LDS write lands global chunk c^(row&7) at chunk c.
    const int sr  = t >> 3;
    const int scs = (((t & 7) ^ (sr & 7)) * 8);
    const size_t arow0 = (size_t)(rb * 128 + sr) * DK_ + scs;
    const size_t brow0 = (size_t)(cb * 128 + sr) * DK_ + scs;

    // mask staging: thread t -> patch row t>>4 (of 16 per kt), cols (t&15)*8..+7
    const int mr = t >> 4;
    const int mc = t & 15;
    const int* mbase  = mask + (size_t)(rb * 128 + mr) * BN_ + cb * 128 + mc * 8;
    const int* mbaseT = mask + (size_t)(cb * 128 + mr) * BN_ + rb * 128 + mc * 8;

    const int r16 = lane & 15;
    const int g4  = lane >> 4;
    const int r7  = r16 & 7;

#define STAGE(kt)                                                                          \
    {                                                                                      \
        const int k0_ = (kt) * 64;                                                         \
        _Pragma("unroll")                                                                  \
        for (int s = 0; s < 4; ++s) {                                                      \
            __builtin_amdgcn_global_load_lds(                                              \
                (const __attribute__((address_space(1))) void*)(ebf + arow0 + (size_t)s * 32 * DK_ + k0_), \
                (__attribute__((address_space(3))) void*)(As + s * 2048 + t * 8),          \
                16, 0, 0);                                                                 \
        }                                                                                  \
        _Pragma("unroll")                                                                  \
        for (int s = 0; s < 4; ++s) {                                                      \
            __builtin_amdgcn_global_load_lds(                                              \
                (const __attribute__((address_space(1))) void*)(ebf + brow0 + (size_t)s * 32 * DK_ + k0_), \
                (__attribute__((address_space(3))) void*)(Bs + s * 2048 + t * 8),          \
                16, 0, 0);                                                                 \
        }                                                                                  \
    }

    int4 m0[2], m1[2], n0[2], n1[2];   // 1-phase-deep pipelines, both orientations

    // prologue: mask(0) row + T in flight (oldest in queue)
    { const int4* p = reinterpret_cast<const int4*>(mbase);  m0[0] = p[0]; m1[0] = p[1]; }
    asm volatile("" ::: "memory");
    { const int4* p = reinterpret_cast<const int4*>(mbaseT); n0[0] = p[0]; n1[0] = p[1]; }
    asm volatile("" ::: "memory");

#pragma unroll
    for (int kt = 0; kt < 8; ++kt) {
        STAGE(kt);
        asm volatile("" ::: "memory");
        if (kt < 7) {   // issue mask(kt+1) both orientations: the 4 newest at the wait
            const int4* p = reinterpret_cast<const int4*>(mbase + (size_t)(kt + 1) * 16 * BN_);
            m0[(kt + 1) & 1] = p[0];
            m1[(kt + 1) & 1] = p[1];
            asm volatile("" ::: "memory");
            const int4* q = reinterpret_cast<const int4*>(mbaseT + (size_t)(kt + 1) * 16 * BN_);
            n0[(kt + 1) & 1] = q[0];
            n1[(kt + 1) & 1] = q[1];
        }
        asm volatile("" ::: "memory");
        if (kt < 7) { asm volatile("s_waitcnt vmcnt(4)" ::: "memory"); }
        else        { asm volatile("s_waitcnt vmcnt(0)" ::: "memory"); }
        __builtin_amdgcn_s_barrier();            // top barrier: stage(kt)+mask(kt) ready
        __builtin_amdgcn_sched_barrier(0);

        // pack mask(kt), both orientations (complete: older than stage(kt))
        {
            const int4 a = m0[kt & 1], b = m1[kt & 1];
            unsigned by = (unsigned)(a.x != 0)        | ((unsigned)(a.y != 0) << 1)
                        | ((unsigned)(a.z != 0) << 2) | ((unsigned)(a.w != 0) << 3)
                        | ((unsigned)(b.x != 0) << 4) | ((unsigned)(b.y != 0) << 5)
                        | ((unsigned)(b.z != 0) << 6) | ((unsigned)(b.w != 0) << 7);
            pmB[(kt * 16 + mr) * 16 + mc] = (unsigned char)by;
            const int4 c = n0[kt & 1], d = n1[kt & 1];
            unsigned byT = (unsigned)(c.x != 0)        | ((unsigned)(c.y != 0) << 1)
                         | ((unsigned)(c.z != 0) << 2) | ((unsigned)(c.w != 0) << 3)
                         | ((unsigned)(d.x != 0) << 4) | ((unsigned)(d.y != 0) << 5)
                         | ((unsigned)(d.z != 0) << 6) | ((unsigned)(d.w != 0) << 7);
            pmBT[(kt * 16 + mr) * 16 + mc] = (unsigned char)byT;
        }

#pragma unroll
        for (int ks = 0; ks < 2; ++ks) {
            bf16x8 af[4], bfr[4];
            const int koff = (((ks * 4 + g4) ^ r7) * 8);   // swizzled chunk within row
#pragma unroll
            for (int fm = 0; fm < 4; ++fm)
                af[fm] = *reinterpret_cast<const bf16x8*>(As + (wr * 64 + fm * 16 + r16) * 64 + koff);
#pragma unroll
            for (int fn = 0; fn < 4; ++fn)
                bfr[fn] = *reinterpret_cast<const bf16x8*>(Bs + (wc * 64 + fn * 16 + r16) * 64 + koff);
#pragma unroll
            for (int fm = 0; fm < 4; ++fm)
#pragma unroll
                for (int fn = 0; fn < 4; ++fn)
                    acc[fm][fn] = __builtin_amdgcn_mfma_f32_16x16x32_bf16(bfr[fn], af[fm], acc[fm][fn], 0, 0, 0);
        }
        __builtin_amdgcn_sched_barrier(0);
        __builtin_amdgcn_s_barrier();            // bottom barrier: buf reads done, no vm drain
        __builtin_amdgcn_sched_barrier(0);
    }
#undef STAGE
    __syncthreads();   // full drain once: bit-tiles visible for the epilogue

    // ---- epilogue: row-side (r11) + col-side via symmetry (r8-verified) ----
    const float C1 = TEMP_INV * LOG2E_;
    const float C2 = -MAXOFF * LOG2E_;
    const int l15 = lane & 15;
    const int gq4 = g4 * 4;

    uint2 rw[4];
#pragma unroll
    for (int fm = 0; fm < 4; ++fm) {
        const uint4 rv = *reinterpret_cast<const uint4*>(pmB + (wr * 64 + fm * 16 + l15) * 16);
        rw[fm].x = wc ? rv.z : rv.x;
        rw[fm].y = wc ? rv.w : rv.y;
    }
    float lseA[4] = {0.f, 0.f, 0.f, 0.f};
    float posA[4] = {0.f, 0.f, 0.f, 0.f};

#pragma unroll
    for (int fn = 0; fn < 4; ++fn) {
#pragma unroll
        for (int rg = 0; rg < 4; ++rg) {
            const int jl = wc * 64 + fn * 16 + gq4 + rg;   // local col / cb-row
            uint2 tv;
            if (offd) tv = *reinterpret_cast<const uint2*>(pmBT + jl * 16 + wr * 8);
            float colL = 0.f, colP = 0.f;
#pragma unroll
            for (int fm = 0; fm < 4; ++fm) {
                const float a = acc[fm][fn][rg];
                const bool dg = db && (wr == wc) && (fm == fn) && (l15 == gq4 + rg);
                const float ex = dg ? 0.0f : exp2f(fmaf(a, C1, C2));
                lseA[fm] += ex;
                const unsigned wsel = (fn < 2) ? rw[fm].x : rw[fm].y;
                const bool p = (((wsel >> ((fn & 1) * 16 + gq4 + rg)) & 1u) != 0u) && !dg;
                posA[fm] += p ? a : 0.0f;
                if (offd) {
                    colL += ex;   // symmetric credit: sim(j,i) == sim(i,j)
                    const unsigned cw = (fm < 2) ? tv.x : tv.y;
                    colP += ((cw >> ((fm & 1) * 16 + l15)) & 1u) ? a : 0.0f;
                }
            }
            if (offd) {
#pragma unroll
                for (int off = 1; off < 16; off <<= 1) {
                    colL += __shfl_xor(colL, off, 64);
                    colP += __shfl_xor(colP, off, 64);
                }
                if (l15 == 0) {
                    atomicAdd(&redC[0][jl], colL);
                    atomicAdd(&redC[1][jl], colP * TEMP_INV);
                }
            }
        }
    }
#pragma unroll
    for (int fm = 0; fm < 4; ++fm) {
        float L = lseA[fm], P = posA[fm];
        L += __shfl_xor(L, 16, 64); L += __shfl_xor(L, 32, 64);
        P += __shfl_xor(P, 16, 64); P += __shfl_xor(P, 32, 64);
        if (g4 == 0) {
            const int li = wr * 64 + fm * 16 + l15;
            atomicAdd(&redR[0][li], L);
            atomicAdd(&redR[1][li], P * TEMP_INV);
        }
    }
    __syncthreads();
    if (t < 128) {
        const uint4 rv = *reinterpret_cast<const uint4*>(pmB + t * 16);
        float cnt = (float)(__popc(rv.x) + __popc(rv.y) + __popc(rv.z) + __popc(rv.w));
        if (db) {   // remove diagonal bit (diag col == local row t)
            const unsigned wsel = (t < 64) ? ((t < 32) ? rv.x : rv.y)
                                           : ((t < 96) ? rv.z : rv.w);
            cnt -= (float)((wsel >> (t & 31)) & 1u);
        }
        const int i = rb * 128 + t;
        atomicAdd(&se[i], redR[0][t]);
        atomicAdd(&ps[i], redR[1][t]);
        atomicAdd(&ct[i], cnt);
    } else if (offd) {
        const int r = t - 128;
        const uint4 tvr = *reinterpret_cast<const uint4*>(pmBT + r * 16);
        const float cnt = (float)(__popc(tvr.x) + __popc(tvr.y) + __popc(tvr.z) + __popc(tvr.w));
        const int j = cb * 128 + r;
        atomicAdd(&se[j], redC[0][r]);
        atomicAdd(&ps[j], redC[1][r]);
        atomicAdd(&ct[j], cnt);
    }
}

// ---------------- Kernel 3: finalize scalar loss (32 blocks) ----------------
__global__ __launch_bounds__(256) void finalize_kernel(const float* __restrict__ se,
                                                       const float* __restrict__ ps,
                                                       const float* __restrict__ ct,
                                                       float* __restrict__ out) {
    __shared__ float red[256];
    const int t = threadIdx.x;
    const int i = blockIdx.x * 256 + t;
    const float lse = logf(se[i]) + MAXOFF;
    red[t] = lse - ps[i] / fmaxf(ct[i], 1.0f);
    __syncthreads();
    for (int s = 128; s > 0; s >>= 1) {
        if (t < s) red[t] += red[t + s];
        __syncthreads();
    }
    if (t == 0) atomicAdd(out, red[0] * (1.0f / (float)BN_));
}

extern "C" void kernel_launch(void* const* d_in, const int* in_sizes, int n_in,
                              void* d_out, int out_size, void* d_ws, size_t ws_size,
                              hipStream_t stream) {
    const float* emb  = (const float*)d_in[0];
    const int*   mask = (const int*)d_in[1];
    float* out = (float*)d_out;

    char* ws = (char*)d_ws;
    unsigned short* ebf = (unsigned short*)ws;                  // 8 MB bf16 normalized
    float* se = (float*)(ws + (size_t)8 * 1024 * 1024);
    float* ps = se + BN_;
    float* ct = ps + BN_;

    hipMemsetAsync(se, 0, (size_t)3 * BN_ * sizeof(float), stream);
    hipMemsetAsync(out, 0, sizeof(float), stream);
    norm_kernel<<<BN_ / 4, 256, 0, stream>>>(emb, ebf);
    infonce_main<<<2080, 256, 0, stream>>>(ebf, mask, se, ps, ct);
    finalize_kernel<<<BN_ / 256, 256, 0, stream>>>(se, ps, ct, out);
}

// Round 13
// 137.043 us; speedup vs baseline: 1.5431x; 1.5431x over previous
//
#include <hip/hip_runtime.h>
#include <hip/hip_bf16.h>

// Problem constants (B=8192, D=512 from reference setup_inputs)
#define BN_ 8192
#define DK_ 512
#define TEMP_INV 14.2857142857142857f   // 1/0.07
#define LOG2E_ 1.44269504088896f
#define MAXOFF 15.0f                    // fixed lse offset; |sim| < 14.29 (unit vectors)

typedef __bf16 bf16x8 __attribute__((ext_vector_type(8)));
typedef float f32x4 __attribute__((ext_vector_type(4)));

__device__ inline unsigned short f2bf(float f) {
    unsigned u = __float_as_uint(f);
    return (unsigned short)((u + 0x7FFFu + ((u >> 16) & 1u)) >> 16);
}

// ---------------- Kernel 1: L2-normalize rows, write bf16 ----------------
__global__ __launch_bounds__(256) void norm_kernel(const float* __restrict__ emb,
                                                   unsigned short* __restrict__ ebf) {
    const int row  = blockIdx.x * 4 + (threadIdx.x >> 6);
    const int lane = threadIdx.x & 63;
    const float4* src = reinterpret_cast<const float4*>(emb + (size_t)row * DK_);
    float4 v0 = src[lane];
    float4 v1 = src[lane + 64];
    float ss = v0.x*v0.x + v0.y*v0.y + v0.z*v0.z + v0.w*v0.w
             + v1.x*v1.x + v1.y*v1.y + v1.z*v1.z + v1.w*v1.w;
#pragma unroll
    for (int off = 1; off < 64; off <<= 1) ss += __shfl_xor(ss, off, 64);
    const float scale = 1.0f / fmaxf(sqrtf(ss), 1e-12f);
    uint2 o0, o1;
    o0.x = (unsigned)f2bf(v0.x * scale) | ((unsigned)f2bf(v0.y * scale) << 16);
    o0.y = (unsigned)f2bf(v0.z * scale) | ((unsigned)f2bf(v0.w * scale) << 16);
    o1.x = (unsigned)f2bf(v1.x * scale) | ((unsigned)f2bf(v1.y * scale) << 16);
    o1.y = (unsigned)f2bf(v1.z * scale) | ((unsigned)f2bf(v1.w * scale) << 16);
    uint2* dst = reinterpret_cast<uint2*>(ebf + (size_t)row * DK_);
    dst[lane]      = o0;
    dst[lane + 64] = o1;
}

// ---------------- Kernel 2: full grid, BK=32 DMA double-buffer ----------------
// grid (64,64); 256 threads = 4 waves (wr,wc), each a 64x64 quadrant (16x16x32 frags).
// vs r11 (best, 116.5us): BK 64->32 halves each staging buffer so a DOUBLE buffer
// fits the same 35KB LDS (4 blocks/CU kept).  One barrier per kt; STAGE(kt+1) is
// issued AFTER the top barrier into the idle buffer -> a full compute phase to land
// (removes the per-kt stage-latency stall that r11 ate 8x/tile).  Queue invariant at
// top of kt: [M(kt+1)2, S(kt)4, M(kt+2)2] -> vmcnt(2) completes S(kt)+M(kt) for
// kt<=6; vmcnt(0) for kt>=7 (masks exhausted; S(kt) is one phase old).
// T2 swizzle re-derived for 64B rows: src chunk (t&3)^((t>>3)&3), read chunk
// g4^((r16>>1)&3) -> uniform 16B-slot spread (same class that measured 0 conflicts).
// SWAPPED mfma operands (verified r5/r6): a = acc[fm][fn][rg] is sim(i,j) with
//   i = rb*128 + wr*64 + fm*16 + (lane&15)
//   j = cb*128 + wc*64 + fn*16 + (lane>>4)*4 + rg
__global__ __launch_bounds__(256, 4) void infonce_main(
    const unsigned short* __restrict__ ebf,
    const int* __restrict__ mask,
    float* __restrict__ se, float* __restrict__ ps, float* __restrict__ ct) {

    __shared__ unsigned short As[2][128 * 32];    // 2 x 8KB
    __shared__ unsigned short Bs[2][128 * 32];    // 2 x 8KB
    __shared__ unsigned char  pmB[128 * 16];      // 2KB mask bit-tile
    __shared__ float red2[2][128];                // 1KB row partials {lse, pos}

    const int t    = threadIdx.x;
    const int lane = t & 63;
    const int wid  = t >> 6;
    const int wr   = wid >> 1;
    const int wc   = wid & 1;
    const int rb   = blockIdx.x;
    const int cb   = blockIdx.y;

    if (t < 128) { red2[0][t] = 0.f; red2[1][t] = 0.f; }

    f32x4 acc[4][4] = {};

    // DMA staging map (BK=32): per array 2 instrs; instr s covers rows s*64..+63.
    // thread t -> row (t>>2), 16B chunk (t&3); SRC chunk pre-swizzled ^((t>>3)&3)
    // so linear LDS write lands global chunk c^((row>>1)&3) at chunk c.
    const int drow = t >> 2;
    const int dchk = ((t & 3) ^ ((t >> 3) & 3)) * 8;
    const size_t asrc = (size_t)(rb * 128 + drow) * DK_ + dchk;
    const size_t bsrc = (size_t)(cb * 128 + drow) * DK_ + dchk;

    // mask staging map (kt<8): thread t -> patch row t>>4 (16 rows/kt), cols (t&15)*8
    const int mr = t >> 4;
    const int mc = t & 15;
    const int* mbase = mask + (size_t)(rb * 128 + mr) * BN_ + cb * 128 + mc * 8;

    const int r16 = lane & 15;
    const int g4  = lane >> 4;

#define STAGE(buf, kt)                                                                     \
    {                                                                                      \
        const int k0_ = (kt) * 32;                                                         \
        _Pragma("unroll")                                                                  \
        for (int s = 0; s < 2; ++s) {                                                      \
            __builtin_amdgcn_global_load_lds(                                              \
                (const __attribute__((address_space(1))) void*)(ebf + asrc + (size_t)s * 64 * DK_ + k0_), \
                (__attribute__((address_space(3))) void*)(&As[buf][0] + s * 2048 + t * 8), \
                16, 0, 0);                                                                 \
        }                                                                                  \
        _Pragma("unroll")                                                                  \
        for (int s = 0; s < 2; ++s) {                                                      \
            __builtin_amdgcn_global_load_lds(                                              \
                (const __attribute__((address_space(1))) void*)(ebf + bsrc + (size_t)s * 64 * DK_ + k0_), \
                (__attribute__((address_space(3))) void*)(&Bs[buf][0] + s * 2048 + t * 8), \
                16, 0, 0);                                                                 \
        }                                                                                  \
    }

    int4 m0[2], m1[2];   // 2-deep mask register pipeline (static idx under unroll)

    // prologue (issue order is the vmcnt contract): M0, S0, M1
    { const int4* p = reinterpret_cast<const int4*>(mbase);                     m0[0] = p[0]; m1[0] = p[1]; }
    asm volatile("" ::: "memory");
    STAGE(0, 0);
    asm volatile("" ::: "memory");
    { const int4* p = reinterpret_cast<const int4*>(mbase + (size_t)16 * BN_);  m0[1] = p[0]; m1[1] = p[1]; }
    asm volatile("" ::: "memory");

#pragma unroll
    for (int kt = 0; kt < 16; ++kt) {
        if (kt <= 6) { asm volatile("s_waitcnt vmcnt(2)" ::: "memory"); }
        else         { asm volatile("s_waitcnt vmcnt(0)" ::: "memory"); }
        __builtin_amdgcn_s_barrier();            // buf[kt&1] staged; all waves' loads done
        __builtin_amdgcn_sched_barrier(0);

        // pack mask(kt) for kt<8 (complete: older than S(kt) at the wait)
        if (kt < 8) {
            const int4 a = m0[kt & 1], b = m1[kt & 1];
            unsigned by = (unsigned)(a.x != 0)        | ((unsigned)(a.y != 0) << 1)
                        | ((unsigned)(a.z != 0) << 2) | ((unsigned)(a.w != 0) << 3)
                        | ((unsigned)(b.x != 0) << 4) | ((unsigned)(b.y != 0) << 5)
                        | ((unsigned)(b.z != 0) << 6) | ((unsigned)(b.w != 0) << 7);
            pmB[(kt * 16 + mr) * 16 + mc] = (unsigned char)by;
        }
        // issue next-tile stage into the idle buffer + next-next mask (post-barrier:
        // buf[(kt+1)&1] reads finished last iter, so DMA writes are race-free)
        if (kt < 15) {
            STAGE((kt + 1) & 1, kt + 1);
            asm volatile("" ::: "memory");
            if (kt < 6) {
                const int4* p = reinterpret_cast<const int4*>(mbase + (size_t)(kt + 2) * 16 * BN_);
                m0[kt & 1] = p[0];
                m1[kt & 1] = p[1];
            }
            asm volatile("" ::: "memory");
        }
        __builtin_amdgcn_sched_barrier(0);

        const unsigned short* Ab = &As[kt & 1][0];
        const unsigned short* Bb = &Bs[kt & 1][0];
        {
            bf16x8 af[4], bfr[4];
            const int koff = (g4 ^ ((r16 >> 1) & 3)) * 8;   // swizzled chunk within 64B row
#pragma unroll
            for (int fm = 0; fm < 4; ++fm)
                af[fm] = *reinterpret_cast<const bf16x8*>(Ab + (wr * 64 + fm * 16 + r16) * 32 + koff);
#pragma unroll
            for (int fn = 0; fn < 4; ++fn)
                bfr[fn] = *reinterpret_cast<const bf16x8*>(Bb + (wc * 64 + fn * 16 + r16) * 32 + koff);
#pragma unroll
            for (int fm = 0; fm < 4; ++fm)
#pragma unroll
                for (int fn = 0; fn < 4; ++fn)
                    acc[fm][fn] = __builtin_amdgcn_mfma_f32_16x16x32_bf16(bfr[fn], af[fm], acc[fm][fn], 0, 0, 0);
        }
        __builtin_amdgcn_sched_barrier(0);
        // no bottom barrier: next iter's top barrier orders reads vs the restage
    }
#undef STAGE
    __syncthreads();   // full drain (incl. lgkm): pmB visible for the epilogue

    // ---- epilogue (r11 verbatim): swapped layout -> in-lane row sums ----
    const float C1 = TEMP_INV * LOG2E_;
    const float C2 = -MAXOFF * LOG2E_;
    const bool  db  = (rb == cb);
    const int   gq4 = (lane >> 4) * 4;

#pragma unroll
    for (int fm = 0; fm < 4; ++fm) {
        const int li = wr * 64 + fm * 16 + (lane & 15);
        const uint4 rv = *reinterpret_cast<const uint4*>(pmB + li * 16);
        const unsigned w0 = wc ? rv.z : rv.x;   // this wave's 64-col window, bits 0..31
        const unsigned w1 = wc ? rv.w : rv.y;   // bits 32..63
        float lsep = 0.f, posp = 0.f;
#pragma unroll
        for (int fn = 0; fn < 4; ++fn) {
            const unsigned wsel = (fn < 2) ? w0 : w1;
#pragma unroll
            for (int rg = 0; rg < 4; ++rg) {
                const float a = acc[fm][fn][rg];
                const bool dg = db && (wr == wc) && (fm == fn) && ((lane & 15) == gq4 + rg);
                const float ex = dg ? 0.0f : exp2f(fmaf(a, C1, C2));
                lsep += ex;
                const bool p = (((wsel >> ((fn & 1) * 16 + gq4 + rg)) & 1u) != 0u) && !dg;
                posp += p ? a : 0.0f;
            }
        }
        lsep += __shfl_xor(lsep, 16, 64); lsep += __shfl_xor(lsep, 32, 64);
        posp += __shfl_xor(posp, 16, 64); posp += __shfl_xor(posp, 32, 64);
        if ((lane >> 4) == 0) {
            atomicAdd(&red2[0][li], lsep);                 // ds atomic, cross-wc merge
            atomicAdd(&red2[1][li], posp * TEMP_INV);
        }
    }
    __syncthreads();
    if (t < 128) {
        const uint4 rv = *reinterpret_cast<const uint4*>(pmB + t * 16);
        float cnt = (float)(__popc(rv.x) + __popc(rv.y) + __popc(rv.z) + __popc(rv.w));
        if (db) {   // remove diagonal bit from count (diag col == local row t)
            const unsigned wsel = (t < 64) ? ((t < 32) ? rv.x : rv.y)
                                           : ((t < 96) ? rv.z : rv.w);
            cnt -= (float)((wsel >> (t & 31)) & 1u);
        }
        const int i = rb * 128 + t;
        atomicAdd(&se[i], red2[0][t]);
        atomicAdd(&ps[i], red2[1][t]);
        atomicAdd(&ct[i], cnt);
    }
}

// ---------------- Kernel 3: finalize scalar loss (32 blocks) ----------------
__global__ __launch_bounds__(256) void finalize_kernel(const float* __restrict__ se,
                                                       const float* __restrict__ ps,
                                                       const float* __restrict__ ct,
                                                       float* __restrict__ out) {
    __shared__ float red[256];
    const int t = threadIdx.x;
    const int i = blockIdx.x * 256 + t;
    const float lse = logf(se[i]) + MAXOFF;
    red[t] = lse - ps[i] / fmaxf(ct[i], 1.0f);
    __syncthreads();
    for (int s = 128; s > 0; s >>= 1) {
        if (t < s) red[t] += red[t + s];
        __syncthreads();
    }
    if (t == 0) atomicAdd(out, red[0] * (1.0f / (float)BN_));
}

extern "C" void kernel_launch(void* const* d_in, const int* in_sizes, int n_in,
                              void* d_out, int out_size, void* d_ws, size_t ws_size,
                              hipStream_t stream) {
    const float* emb  = (const float*)d_in[0];
    const int*   mask = (const int*)d_in[1];
    float* out = (float*)d_out;

    char* ws = (char*)d_ws;
    unsigned short* ebf = (unsigned short*)ws;                  // 8 MB bf16 normalized
    float* se = (float*)(ws + (size_t)8 * 1024 * 1024);
    float* ps = se + BN_;
    float* ct = ps + BN_;

    hipMemsetAsync(se, 0, (size_t)3 * BN_ * sizeof(float), stream);
    hipMemsetAsync(out, 0, sizeof(float), stream);
    norm_kernel<<<BN_ / 4, 256, 0, stream>>>(emb, ebf);
    infonce_main<<<dim3(64, 64), 256, 0, stream>>>(ebf, mask, se, ps, ct);
    finalize_kernel<<<BN_ / 256, 256, 0, stream>>>(se, ps, ct, out);
}